// Round 7
// baseline (11548.649 us; speedup 1.0000x reference)
//
#include <hip/hip_runtime.h>
#include <math.h>

namespace {
constexpr int kV = 12001;
constexpr int kE = 300;
constexpr int kR = 1024;
constexpr int kH = 512;
constexpr int kF = 2048;
constexpr int kB = 64;
constexpr int kT = 20;
constexpr int kL = 196;
constexpr int kNB = 512;   // persistent grid blocks
}

typedef __attribute__((ext_vector_type(8))) short short8;
typedef __attribute__((ext_vector_type(4))) float f32x4;

__device__ __forceinline__ unsigned short f2bf(float f) {
    unsigned u = __builtin_bit_cast(unsigned, f);
    u = (u + 0x7fffu + ((u >> 16) & 1u)) >> 16;
    return (unsigned short)u;
}
__device__ __forceinline__ float bf2f(unsigned short h) {
    unsigned u = ((unsigned)h) << 16;
    return __builtin_bit_cast(float, u);
}

// ---------------------------------------------------------------------------
// Split-bf16 MFMA GEMM (fp32 in/out, ~fp32 accuracy), 128x128 tile, BK=32.
// ---------------------------------------------------------------------------
template<bool GATHER>
__global__ __launch_bounds__(256)
void gemm_split_kernel(const float* __restrict__ A, int lda,
                       const float* __restrict__ W, int ldw,
                       const float* __restrict__ bias,
                       float* __restrict__ C, int ldc,
                       int M, int N, int K,
                       const int* __restrict__ ridx)
{
    __shared__ unsigned short sAh[128][40];
    __shared__ unsigned short sAl[128][40];
    __shared__ unsigned short sWh[128][40];
    __shared__ unsigned short sWl[128][40];
    const int tid = threadIdx.x;
    const int m0 = blockIdx.y * 128;
    const int n0 = blockIdx.x * 128;
    const int wave = tid >> 6, lane = tid & 63;
    const int wm = wave >> 1, wn = wave & 1;
    const int lrow = lane & 15, lkg = lane >> 4;

    f32x4 acc[4][4];
    #pragma unroll
    for (int mi = 0; mi < 4; ++mi)
        #pragma unroll
        for (int ni = 0; ni < 4; ++ni)
            acc[mi][ni] = (f32x4){0.f, 0.f, 0.f, 0.f};

    for (int k0 = 0; k0 < K; k0 += 32) {
        for (int g = tid; g < 512; g += 256) {
            const int r = g >> 2, q = g & 3;
            const int k = k0 + q * 8;
            short8 vh = (short8){0,0,0,0,0,0,0,0};
            short8 vl = (short8){0,0,0,0,0,0,0,0};
            const int m = m0 + r;
            if (m < M && k < K) {
                const int row = GATHER ? ridx[m] : m;
                const float* src = A + (size_t)row * lda + k;
                float va[8];
                if (k + 8 <= K) {
                    float4 f0 = *(const float4*)src;
                    float4 f1 = *(const float4*)(src + 4);
                    va[0]=f0.x; va[1]=f0.y; va[2]=f0.z; va[3]=f0.w;
                    va[4]=f1.x; va[5]=f1.y; va[6]=f1.z; va[7]=f1.w;
                } else {
                    #pragma unroll
                    for (int j = 0; j < 8; ++j) va[j] = (k + j < K) ? src[j] : 0.f;
                }
                #pragma unroll
                for (int j = 0; j < 8; ++j) {
                    const unsigned short hi = f2bf(va[j]);
                    ((short*)&vh)[j] = (short)hi;
                    ((short*)&vl)[j] = (short)f2bf(va[j] - bf2f(hi));
                }
            }
            *(short8*)&sAh[r][q * 8] = vh;
            *(short8*)&sAl[r][q * 8] = vl;
        }
        for (int g = tid; g < 512; g += 256) {
            const int r = g >> 2, q = g & 3;
            const int k = k0 + q * 8;
            short8 vh = (short8){0,0,0,0,0,0,0,0};
            short8 vl = (short8){0,0,0,0,0,0,0,0};
            const int n = n0 + r;
            if (n < N && k < K) {
                const float* src = W + (size_t)n * ldw + k;
                float va[8];
                if (k + 8 <= K) {
                    float4 f0 = *(const float4*)src;
                    float4 f1 = *(const float4*)(src + 4);
                    va[0]=f0.x; va[1]=f0.y; va[2]=f0.z; va[3]=f0.w;
                    va[4]=f1.x; va[5]=f1.y; va[6]=f1.z; va[7]=f1.w;
                } else {
                    #pragma unroll
                    for (int j = 0; j < 8; ++j) va[j] = (k + j < K) ? src[j] : 0.f;
                }
                #pragma unroll
                for (int j = 0; j < 8; ++j) {
                    const unsigned short hi = f2bf(va[j]);
                    ((short*)&vh)[j] = (short)hi;
                    ((short*)&vl)[j] = (short)f2bf(va[j] - bf2f(hi));
                }
            }
            *(short8*)&sWh[r][q * 8] = vh;
            *(short8*)&sWl[r][q * 8] = vl;
        }
        __syncthreads();

        short8 ah[4], al[4], bh[4], bl[4];
        #pragma unroll
        for (int mi = 0; mi < 4; ++mi) {
            ah[mi] = *(const short8*)&sAh[wm * 64 + mi * 16 + lrow][lkg * 8];
            al[mi] = *(const short8*)&sAl[wm * 64 + mi * 16 + lrow][lkg * 8];
        }
        #pragma unroll
        for (int ni = 0; ni < 4; ++ni) {
            bh[ni] = *(const short8*)&sWh[wn * 64 + ni * 16 + lrow][lkg * 8];
            bl[ni] = *(const short8*)&sWl[wn * 64 + ni * 16 + lrow][lkg * 8];
        }
        #pragma unroll
        for (int mi = 0; mi < 4; ++mi)
            #pragma unroll
            for (int ni = 0; ni < 4; ++ni) {
                acc[mi][ni] = __builtin_amdgcn_mfma_f32_16x16x32_bf16(ah[mi], bh[ni], acc[mi][ni], 0, 0, 0);
                acc[mi][ni] = __builtin_amdgcn_mfma_f32_16x16x32_bf16(ah[mi], bl[ni], acc[mi][ni], 0, 0, 0);
                acc[mi][ni] = __builtin_amdgcn_mfma_f32_16x16x32_bf16(al[mi], bh[ni], acc[mi][ni], 0, 0, 0);
            }
        __syncthreads();
    }

    #pragma unroll
    for (int mi = 0; mi < 4; ++mi) {
        const int mbase = m0 + wm * 64 + mi * 16 + lkg * 4;
        #pragma unroll
        for (int ni = 0; ni < 4; ++ni) {
            const int n = n0 + wn * 64 + ni * 16 + lrow;
            if (n >= N) continue;
            const float bb = bias ? bias[n] : 0.f;
            #pragma unroll
            for (int r = 0; r < 4; ++r) {
                const int m = mbase + r;
                if (m >= M) continue;
                C[(size_t)m * ldc + n] = acc[mi][ni][r] + bb;
            }
        }
    }
}

// ---------------------------------------------------------------------------
// Grid barrier: sense-reversing, AGENT-scope atomics, 8-way spread counters.
// bar layout: cnt[q]=bar[q*16] (q=0..7), gen=bar[128].
// ---------------------------------------------------------------------------
__device__ __forceinline__ void gbar(unsigned* bar, int blk)
{
    __syncthreads();
    if (threadIdx.x == 0) {
        unsigned* gen = bar + 128;
        __threadfence();   // flush this block's prior global writes (agent scope)
        const unsigned g = __hip_atomic_load(gen, __ATOMIC_RELAXED, __HIP_MEMORY_SCOPE_AGENT);
        __hip_atomic_fetch_add(bar + (blk & 7) * 16, 1u, __ATOMIC_ACQ_REL, __HIP_MEMORY_SCOPE_AGENT);
        if (blk == 0) {
            for (;;) {
                unsigned s = 0;
                #pragma unroll
                for (int q = 0; q < 8; ++q)
                    s += __hip_atomic_load(bar + q * 16, __ATOMIC_ACQUIRE, __HIP_MEMORY_SCOPE_AGENT);
                if (s == (unsigned)kNB) break;
                __builtin_amdgcn_s_sleep(1);
            }
            #pragma unroll
            for (int q = 0; q < 8; ++q)
                __hip_atomic_store(bar + q * 16, 0u, __ATOMIC_RELAXED, __HIP_MEMORY_SCOPE_AGENT);
            __hip_atomic_store(gen, g + 1u, __ATOMIC_RELEASE, __HIP_MEMORY_SCOPE_AGENT);
        } else {
            while (__hip_atomic_load(gen, __ATOMIC_ACQUIRE, __HIP_MEMORY_SCOPE_AGENT) == g)
                __builtin_amdgcn_s_sleep(1);
        }
        __threadfence();
    }
    __syncthreads();
}

// ---------------------------------------------------------------------------
// Persistent 20-step recurrence. 512 blocks x 256 threads, 2 blocks/CU.
// Phases per step: A att_h | B e | CD softmax+att_res | E lstm+gates.
// ---------------------------------------------------------------------------
__global__ __launch_bounds__(256, 2)
void step_persistent_kernel(const float* __restrict__ p_att,
                            const float* __restrict__ att_feats,
                            const float* __restrict__ h2att_w,
                            const float* __restrict__ h2att_b,
                            const float* __restrict__ alpha_w,
                            const float* __restrict__ alpha_b,
                            const float* __restrict__ h2h_w,
                            const float* __restrict__ h2h_b,
                            const float* __restrict__ a2c_w,
                            const float* __restrict__ a2c_b,
                            const float* __restrict__ i2h_pre,
                            float* __restrict__ att_h,
                            float* __restrict__ e_buf,
                            float* __restrict__ att_res,
                            float* __restrict__ h0,
                            float* __restrict__ h1,
                            float* __restrict__ cbuf,
                            float* __restrict__ h_all,
                            unsigned* __restrict__ bar)
{
    const int blk = blockIdx.x;
    const int tid = threadIdx.x;
    const int wave = tid >> 6, lane = tid & 63;

    __shared__ union {
        struct { float h8[8][1024]; } pa;                  // 32 KB
        struct { float wsm[kL]; float red[256]; } pcd;     // 1.8 KB
        struct { float hs[64][68]; float ws[10][68]; } pe; // 20.1 KB
    } sm;

    for (int t = 0; t < kT; ++t) {
        const float* h_in  = (t & 1) ? h1 : h0;
        float*       h_out = (t & 1) ? h0 : h1;

        // ---- Phase A: att_h[b,j] = h_in[b,:]·h2att_w[j,:] + b. 64 jc x 8 bg ----
        {
            const int jc = blk >> 3, bg = blk & 7;
            const int b0 = bg * 8;
            for (int i = tid; i < 2048; i += 256) {
                const int bb = i >> 8, c4 = (i & 255) * 4;
                *(float4*)&sm.pa.h8[bb][c4] = *(const float4*)&h_in[(b0 + bb) * kR + c4];
            }
            __syncthreads();
            const int jbase = jc * 8 + wave * 2;
            #pragma unroll
            for (int jj = 0; jj < 2; ++jj) {
                const int j = jbase + jj;
                const float4* wr = (const float4*)(h2att_w + (size_t)j * kR);
                float acc[8] = {0.f,0.f,0.f,0.f,0.f,0.f,0.f,0.f};
                #pragma unroll
                for (int it = 0; it < 4; ++it) {
                    const float4 wv = wr[it * 64 + lane];
                    #pragma unroll
                    for (int bb = 0; bb < 8; ++bb) {
                        const float4 hv = *(const float4*)&sm.pa.h8[bb][(it * 64 + lane) * 4];
                        acc[bb] += wv.x*hv.x + wv.y*hv.y + wv.z*hv.z + wv.w*hv.w;
                    }
                }
                #pragma unroll
                for (int bb = 0; bb < 8; ++bb) {
                    float v = acc[bb];
                    #pragma unroll
                    for (int off = 32; off; off >>= 1) v += __shfl_xor(v, off, 64);
                    acc[bb] = v;
                }
                if (lane == 0) {
                    const float bj = h2att_b[j];
                    #pragma unroll
                    for (int bb = 0; bb < 8; ++bb)
                        att_h[(b0 + bb) * kH + j] = acc[bb] + bj;
                }
            }
        }
        gbar(bar, blk);

        // ---- Phase B: e[row] = sum_h tanh(p_att + att_h)*alpha ----
        for (int row = blk * 4 + wave; row < kB * kL; row += kNB * 4) {
            const int b = row / kL;
            const float* pr = p_att + (size_t)row * kH + lane * 8;
            const float* ah = att_h + b * kH + lane * 8;
            const float* aw = alpha_w + lane * 8;
            float4 p0 = *(const float4*)pr;
            float4 p1 = *(const float4*)(pr + 4);
            float acc = 0.f;
            const float* pv = (const float*)&p0;
            #pragma unroll
            for (int j = 0; j < 4; ++j) acc += tanhf(pv[j] + ah[j]) * aw[j];
            const float* pw = (const float*)&p1;
            #pragma unroll
            for (int j = 0; j < 4; ++j) acc += tanhf(pw[j] + ah[4 + j]) * aw[4 + j];
            #pragma unroll
            for (int off = 32; off; off >>= 1) acc += __shfl_down(acc, off, 64);
            if (lane == 0) e_buf[row] = acc + alpha_b[0];
        }
        gbar(bar, blk);

        // ---- Phase CD: softmax over L (redundant per fc) + att_res ----
        {
            const int b = blk >> 3, fc = blk & 7;
            const float v = (tid < kL) ? e_buf[b * kL + tid] : -1e30f;
            sm.pcd.red[tid] = v; __syncthreads();
            for (int s2 = 128; s2 > 0; s2 >>= 1) {
                if (tid < s2) sm.pcd.red[tid] = fmaxf(sm.pcd.red[tid], sm.pcd.red[tid + s2]);
                __syncthreads();
            }
            const float mx = sm.pcd.red[0]; __syncthreads();
            const float ex = (tid < kL) ? expf(v - mx) : 0.f;
            sm.pcd.red[tid] = ex; __syncthreads();
            for (int s2 = 128; s2 > 0; s2 >>= 1) {
                if (tid < s2) sm.pcd.red[tid] += sm.pcd.red[tid + s2];
                __syncthreads();
            }
            const float isum = 1.f / sm.pcd.red[0]; __syncthreads();
            if (tid < kL) sm.pcd.wsm[tid] = ex * isum;
            __syncthreads();
            const int f = fc * 256 + tid;
            const float* af = att_feats + (size_t)b * kL * kF + f;
            float acc = 0.f;
            #pragma unroll 8
            for (int l = 0; l < kL; ++l) acc += sm.pcd.wsm[l] * af[(size_t)l * kF];
            att_res[b * kF + f] = acc;
        }
        gbar(bar, blk);

        // ---- Phase E: h2h + a2c + i2h_pre -> gates -> h_out, c, h_all ----
        {
            const int bq = tid >> 4, s = tid & 15;
            const int rc0 = blk * 2;
            const int kk = s * 4;
            float acc[4][10];
            #pragma unroll
            for (int i = 0; i < 4; ++i)
                #pragma unroll
                for (int rw = 0; rw < 10; ++rw) acc[i][rw] = 0.f;

            for (int k0 = 0; k0 < kR; k0 += 64) {
                for (int i = tid; i < 1024; i += 256) {
                    const int bl = i >> 4, c4 = (i & 15) * 4;
                    *(float4*)&sm.pe.hs[bl][c4] = *(const float4*)&h_in[bl * kR + k0 + c4];
                }
                for (int i = tid; i < 160; i += 256) {
                    const int rw = i >> 4, c4 = (i & 15) * 4;
                    *(float4*)&sm.pe.ws[rw][c4] =
                        *(const float4*)&h2h_w[(size_t)((rw >> 1) * kR + rc0 + (rw & 1)) * kR + k0 + c4];
                }
                __syncthreads();
                float4 hv[4];
                #pragma unroll
                for (int i = 0; i < 4; ++i) hv[i] = *(const float4*)&sm.pe.hs[bq * 4 + i][kk];
                #pragma unroll
                for (int rw = 0; rw < 10; ++rw) {
                    const float4 wv = *(const float4*)&sm.pe.ws[rw][kk];
                    #pragma unroll
                    for (int i = 0; i < 4; ++i)
                        acc[i][rw] += hv[i].x * wv.x + hv[i].y * wv.y + hv[i].z * wv.z + hv[i].w * wv.w;
                }
                __syncthreads();
            }
            for (int k0 = 0; k0 < kF; k0 += 64) {
                for (int i = tid; i < 1024; i += 256) {
                    const int bl = i >> 4, c4 = (i & 15) * 4;
                    *(float4*)&sm.pe.hs[bl][c4] = *(const float4*)&att_res[bl * kF + k0 + c4];
                }
                for (int i = tid; i < 64; i += 256) {
                    const int rw = i >> 4, c4 = (i & 15) * 4;
                    *(float4*)&sm.pe.ws[rw][c4] =
                        *(const float4*)&a2c_w[(size_t)((rw >> 1) * kR + rc0 + (rw & 1)) * kF + k0 + c4];
                }
                __syncthreads();
                float4 av[4];
                #pragma unroll
                for (int i = 0; i < 4; ++i) av[i] = *(const float4*)&sm.pe.hs[bq * 4 + i][kk];
                #pragma unroll
                for (int rw = 0; rw < 4; ++rw) {
                    const float4 wv = *(const float4*)&sm.pe.ws[rw][kk];
                    #pragma unroll
                    for (int i = 0; i < 4; ++i)
                        acc[i][6 + rw] += av[i].x * wv.x + av[i].y * wv.y + av[i].z * wv.z + av[i].w * wv.w;
                }
                __syncthreads();
            }
            #pragma unroll
            for (int i = 0; i < 4; ++i)
                #pragma unroll
                for (int rw = 0; rw < 10; ++rw) {
                    float v = acc[i][rw];
                    v += __shfl_xor(v, 1, 64); v += __shfl_xor(v, 2, 64);
                    v += __shfl_xor(v, 4, 64); v += __shfl_xor(v, 8, 64);
                    acc[i][rw] = v;
                }
            if (s == 0) {
                #pragma unroll
                for (int i = 0; i < 4; ++i) {
                    const int b = bq * 4 + i;
                    const float* ib = i2h_pre + (size_t)(b * kT + t) * (5 * kR);
                    #pragma unroll
                    for (int rr = 0; rr < 2; ++rr) {
                        const int r = rc0 + rr;
                        const float S0 = acc[i][0 + rr] + ib[r]          + h2h_b[r];
                        const float S1 = acc[i][2 + rr] + ib[kR + r]     + h2h_b[kR + r];
                        const float S2 = acc[i][4 + rr] + ib[2 * kR + r] + h2h_b[2 * kR + r];
                        const float S3 = acc[i][6 + rr] + ib[3 * kR + r] + h2h_b[3 * kR + r] + a2c_b[r];
                        const float S4 = acc[i][8 + rr] + ib[4 * kR + r] + h2h_b[4 * kR + r] + a2c_b[kR + r];
                        const float ing = 1.f / (1.f + expf(-S0));
                        const float fg  = 1.f / (1.f + expf(-S1));
                        const float og  = 1.f / (1.f + expf(-S2));
                        const float gg  = fmaxf(S3, S4);
                        const float nc  = fg * cbuf[b * kR + r] + ing * gg;
                        const float nh  = og * tanhf(nc);
                        cbuf[b * kR + r] = nc;
                        h_out[b * kR + r] = nh;
                        h_all[(size_t)(b * kT + t) * kR + r] = nh;
                    }
                }
            }
        }
        gbar(bar, blk);
    }
}

// ---------------------------------------------------------------------------
// in-place log_softmax over V; one block per row (grid = kB*kT)
// ---------------------------------------------------------------------------
__global__ __launch_bounds__(256)
void log_softmax_kernel(float* __restrict__ out)
{
    __shared__ float red[256];
    const int tid = threadIdx.x;
    float* row = out + (size_t)blockIdx.x * kV;

    float mx = -1e30f;
    for (int v = tid; v < kV; v += 256) mx = fmaxf(mx, row[v]);
    red[tid] = mx; __syncthreads();
    for (int s = 128; s > 0; s >>= 1) {
        if (tid < s) red[tid] = fmaxf(red[tid], red[tid + s]);
        __syncthreads();
    }
    mx = red[0];
    __syncthreads();

    float sum = 0.f;
    for (int v = tid; v < kV; v += 256) sum += expf(row[v] - mx);
    red[tid] = sum; __syncthreads();
    for (int s = 128; s > 0; s >>= 1) {
        if (tid < s) red[tid] += red[tid + s];
        __syncthreads();
    }
    const float ls = mx + logf(red[0]);

    for (int v = tid; v < kV; v += 256) row[v] -= ls;
}

extern "C" void kernel_launch(void* const* d_in, const int* in_sizes, int n_in,
                              void* d_out, int out_size, void* d_ws, size_t ws_size,
                              hipStream_t stream)
{
    const int*   seq       = (const int*)  d_in[0];
    const float* att_feats = (const float*)d_in[1];
    const float* embed_w   = (const float*)d_in[2];
    const float* ctx2att_w = (const float*)d_in[3];
    const float* ctx2att_b = (const float*)d_in[4];
    const float* h2att_w   = (const float*)d_in[5];
    const float* h2att_b   = (const float*)d_in[6];
    const float* alpha_w   = (const float*)d_in[7];
    const float* alpha_b   = (const float*)d_in[8];
    const float* i2h_w     = (const float*)d_in[9];
    const float* i2h_b     = (const float*)d_in[10];
    const float* h2h_w     = (const float*)d_in[11];
    const float* h2h_b     = (const float*)d_in[12];
    const float* a2c_w     = (const float*)d_in[13];
    const float* a2c_b     = (const float*)d_in[14];
    const float* logit_w   = (const float*)d_in[15];
    const float* logit_b   = (const float*)d_in[16];
    float* out = (float*)d_out;

    float* ws = (float*)d_ws;
    size_t off = 0;
    auto alloc = [&](size_t nf) { float* p = ws + off; off += (nf + 3) & ~(size_t)3; return p; };

    float* p_att   = alloc((size_t)kB * kL * kH);       // 12544 x 512
    float* i2h_pre = alloc((size_t)kB * kT * 5 * kR);   // 1280 x 5120
    float* h_all   = alloc((size_t)kB * kT * kR);       // 1280 x 1024
    float* att_h   = alloc((size_t)kB * kH);
    float* e_buf   = alloc((size_t)kB * kL);
    float* att_res = alloc((size_t)kB * kF);
    float* h0      = alloc((size_t)kB * kR);
    float* h1      = alloc((size_t)kB * kR);
    float* cbuf    = alloc((size_t)kB * kR);
    unsigned* bar  = (unsigned*)alloc(256);             // barrier state

    hipMemsetAsync(h0,   0, (size_t)kB * kR * sizeof(float), stream);
    hipMemsetAsync(cbuf, 0, (size_t)kB * kR * sizeof(float), stream);
    hipMemsetAsync(bar,  0, 256 * sizeof(unsigned), stream);

    // p_att = att_feats @ ctx2att_w.T + b  (12544 x 512, K=2048)
    gemm_split_kernel<false><<<dim3(kH / 128, kB * kL / 128), 256, 0, stream>>>(
        att_feats, kF, ctx2att_w, kF, ctx2att_b, p_att, kH, kB * kL, kH, kF, nullptr);

    // i2h_pre = embed[seq] @ i2h_w.T + b   (1280 x 5120, K=300)
    gemm_split_kernel<true><<<dim3(5 * kR / 128, kB * kT / 128), 256, 0, stream>>>(
        embed_w, kE, i2h_w, kE, i2h_b, i2h_pre, 5 * kR, kB * kT, 5 * kR, kE, seq);

    // persistent 20-step recurrence (hand-rolled grid barrier; plain launch)
    step_persistent_kernel<<<dim3(kNB), 256, 0, stream>>>(
        p_att, att_feats, h2att_w, h2att_b, alpha_w, alpha_b,
        h2h_w, h2h_b, a2c_w, a2c_b, i2h_pre,
        att_h, e_buf, att_res, h0, h1, cbuf, h_all, bar);

    // logits = h_all @ logit_w.T + b  (1280 x 12001, K=1024) -> out fp32
    gemm_split_kernel<false><<<dim3((kV + 127) / 128, kB * kT / 128), 256, 0, stream>>>(
        h_all, kR, logit_w, kR, logit_b, out, kV, kB * kT, kV, kR, nullptr);

    log_softmax_kernel<<<dim3(kB * kT), 256, 0, stream>>>(out);
}

// Round 8
// 4594.404 us; speedup vs baseline: 2.5136x; 2.5136x over previous
//
#include <hip/hip_runtime.h>
#include <math.h>

namespace {
constexpr int kV = 12001;
constexpr int kE = 300;
constexpr int kR = 1024;
constexpr int kH = 512;
constexpr int kF = 2048;
constexpr int kB = 64;
constexpr int kT = 20;
constexpr int kL = 196;
}

typedef __attribute__((ext_vector_type(8))) short short8;
typedef __attribute__((ext_vector_type(4))) float f32x4;

__device__ __forceinline__ unsigned short f2bf(float f) {
    unsigned u = __builtin_bit_cast(unsigned, f);
    u = (u + 0x7fffu + ((u >> 16) & 1u)) >> 16;
    return (unsigned short)u;
}
__device__ __forceinline__ float bf2f(unsigned short h) {
    unsigned u = ((unsigned)h) << 16;
    return __builtin_bit_cast(float, u);
}
__device__ __forceinline__ float fast_tanh(float x) {
    x = fminf(15.f, fmaxf(-15.f, x));
    const float e = __expf(2.f * x);
    return (e - 1.f) / (e + 1.f);
}
__device__ __forceinline__ float fast_sig(float x) {
    return 1.f / (1.f + __expf(-x));
}

// ---------------------------------------------------------------------------
// fp32 -> bf16-hi conversion (n4 = count/4)
// ---------------------------------------------------------------------------
__global__ __launch_bounds__(256)
void conv_hi_kernel(const float* __restrict__ in, unsigned short* __restrict__ out, int n4)
{
    for (int i = blockIdx.x * 256 + threadIdx.x; i < n4; i += gridDim.x * 256) {
        const float4 v = ((const float4*)in)[i];
        ushort4 o;
        o.x = f2bf(v.x); o.y = f2bf(v.y); o.z = f2bf(v.z); o.w = f2bf(v.w);
        ((ushort4*)out)[i] = o;
    }
}

// fp32 -> (hi, lo) bf16 pair
__global__ __launch_bounds__(256)
void conv_pair_kernel(const float* __restrict__ in,
                      unsigned short* __restrict__ hi_out,
                      unsigned short* __restrict__ lo_out, int n4)
{
    for (int i = blockIdx.x * 256 + threadIdx.x; i < n4; i += gridDim.x * 256) {
        const float4 v = ((const float4*)in)[i];
        ushort4 h, l;
        h.x = f2bf(v.x); l.x = f2bf(v.x - bf2f(h.x));
        h.y = f2bf(v.y); l.y = f2bf(v.y - bf2f(h.y));
        h.z = f2bf(v.z); l.z = f2bf(v.z - bf2f(h.z));
        h.w = f2bf(v.w); l.w = f2bf(v.w - bf2f(h.w));
        ((ushort4*)hi_out)[i] = h;
        ((ushort4*)lo_out)[i] = l;
    }
}

// ---------------------------------------------------------------------------
// bf16-staged MFMA GEMM. A from (Ah[,Al]) bf16 arrays, W from (Wh,Wl).
// products: Ah*Wh + Ah*Wl (+ Al*Wh if A_PAIR). K % 32 == 0, M % 128 == 0.
// ---------------------------------------------------------------------------
template<bool A_PAIR, bool OUT_BF16>
__global__ __launch_bounds__(256)
void gemm_bf_kernel(const unsigned short* __restrict__ Ah,
                    const unsigned short* __restrict__ Al, int lda,
                    const unsigned short* __restrict__ Wh,
                    const unsigned short* __restrict__ Wl, int ldw,
                    const float* __restrict__ bias,
                    void* __restrict__ Cp, int ldc,
                    int M, int N, int K)
{
    __shared__ unsigned short sAh[128][40];
    __shared__ unsigned short sAl[A_PAIR ? 128 : 1][40];
    __shared__ unsigned short sWh[128][40];
    __shared__ unsigned short sWl[128][40];
    const int tid = threadIdx.x;
    const int m0 = blockIdx.y * 128;
    const int n0 = blockIdx.x * 128;
    const int wave = tid >> 6, lane = tid & 63;
    const int wm = wave >> 1, wn = wave & 1;
    const int lrow = lane & 15, lkg = lane >> 4;

    f32x4 acc[4][4];
    #pragma unroll
    for (int mi = 0; mi < 4; ++mi)
        #pragma unroll
        for (int ni = 0; ni < 4; ++ni)
            acc[mi][ni] = (f32x4){0.f, 0.f, 0.f, 0.f};

    for (int k0 = 0; k0 < K; k0 += 32) {
        for (int g = tid; g < 512; g += 256) {
            const int r = g >> 2, q = g & 3;
            const int k = k0 + q * 8;
            const int m = m0 + r;
            const size_t off = (size_t)m * lda + k;
            *(short8*)&sAh[r][q * 8] = *(const short8*)(Ah + off);
            if (A_PAIR) *(short8*)&sAl[r][q * 8] = *(const short8*)(Al + off);
        }
        for (int g = tid; g < 512; g += 256) {
            const int r = g >> 2, q = g & 3;
            const int k = k0 + q * 8;
            const int n = n0 + r;
            short8 vh = (short8){0,0,0,0,0,0,0,0};
            short8 vl = (short8){0,0,0,0,0,0,0,0};
            if (n < N) {
                const size_t off = (size_t)n * ldw + k;
                vh = *(const short8*)(Wh + off);
                vl = *(const short8*)(Wl + off);
            }
            *(short8*)&sWh[r][q * 8] = vh;
            *(short8*)&sWl[r][q * 8] = vl;
        }
        __syncthreads();

        short8 ah[4], al[4], wh[4], wl[4];
        #pragma unroll
        for (int mi = 0; mi < 4; ++mi) {
            ah[mi] = *(const short8*)&sAh[wm * 64 + mi * 16 + lrow][lkg * 8];
            if (A_PAIR) al[mi] = *(const short8*)&sAl[wm * 64 + mi * 16 + lrow][lkg * 8];
        }
        #pragma unroll
        for (int ni = 0; ni < 4; ++ni) {
            wh[ni] = *(const short8*)&sWh[wn * 64 + ni * 16 + lrow][lkg * 8];
            wl[ni] = *(const short8*)&sWl[wn * 64 + ni * 16 + lrow][lkg * 8];
        }
        #pragma unroll
        for (int mi = 0; mi < 4; ++mi)
            #pragma unroll
            for (int ni = 0; ni < 4; ++ni) {
                acc[mi][ni] = __builtin_amdgcn_mfma_f32_16x16x32_bf16(ah[mi], wh[ni], acc[mi][ni], 0, 0, 0);
                acc[mi][ni] = __builtin_amdgcn_mfma_f32_16x16x32_bf16(ah[mi], wl[ni], acc[mi][ni], 0, 0, 0);
                if (A_PAIR)
                    acc[mi][ni] = __builtin_amdgcn_mfma_f32_16x16x32_bf16(al[mi], wh[ni], acc[mi][ni], 0, 0, 0);
            }
        __syncthreads();
    }

    // epilogue: row = (lane>>4)*4 + reg, col = lane&15 (m89-verified layout)
    #pragma unroll
    for (int mi = 0; mi < 4; ++mi) {
        const int mbase = m0 + wm * 64 + mi * 16 + lkg * 4;
        #pragma unroll
        for (int ni = 0; ni < 4; ++ni) {
            const int n = n0 + wn * 64 + ni * 16 + lrow;
            if (n >= N) continue;
            const float bb = bias ? bias[n] : 0.f;
            #pragma unroll
            for (int r = 0; r < 4; ++r) {
                const int m = mbase + r;
                const float v = acc[mi][ni][r] + bb;
                if (OUT_BF16) ((unsigned short*)Cp)[(size_t)m * ldc + n] = f2bf(v);
                else          ((float*)Cp)[(size_t)m * ldc + n] = v;
            }
        }
    }
}

// ---------------------------------------------------------------------------
// Old split-fp32 GEMM (kept for i2h: gathered fp32 A, K=300 edge)
// ---------------------------------------------------------------------------
template<bool GATHER>
__global__ __launch_bounds__(256)
void gemm_split_kernel(const float* __restrict__ A, int lda,
                       const float* __restrict__ W, int ldw,
                       const float* __restrict__ bias,
                       float* __restrict__ C, int ldc,
                       int M, int N, int K,
                       const int* __restrict__ ridx)
{
    __shared__ unsigned short sAh[128][40];
    __shared__ unsigned short sAl[128][40];
    __shared__ unsigned short sWh[128][40];
    __shared__ unsigned short sWl[128][40];
    const int tid = threadIdx.x;
    const int m0 = blockIdx.y * 128;
    const int n0 = blockIdx.x * 128;
    const int wave = tid >> 6, lane = tid & 63;
    const int wm = wave >> 1, wn = wave & 1;
    const int lrow = lane & 15, lkg = lane >> 4;

    f32x4 acc[4][4];
    #pragma unroll
    for (int mi = 0; mi < 4; ++mi)
        #pragma unroll
        for (int ni = 0; ni < 4; ++ni)
            acc[mi][ni] = (f32x4){0.f, 0.f, 0.f, 0.f};

    for (int k0 = 0; k0 < K; k0 += 32) {
        for (int g = tid; g < 512; g += 256) {
            const int r = g >> 2, q = g & 3;
            const int k = k0 + q * 8;
            short8 vh = (short8){0,0,0,0,0,0,0,0};
            short8 vl = (short8){0,0,0,0,0,0,0,0};
            const int m = m0 + r;
            if (m < M && k < K) {
                const int row = GATHER ? ridx[m] : m;
                const float* src = A + (size_t)row * lda + k;
                float va[8];
                #pragma unroll
                for (int j = 0; j < 8; ++j) va[j] = (k + j < K) ? src[j] : 0.f;
                #pragma unroll
                for (int j = 0; j < 8; ++j) {
                    const unsigned short hi = f2bf(va[j]);
                    ((short*)&vh)[j] = (short)hi;
                    ((short*)&vl)[j] = (short)f2bf(va[j] - bf2f(hi));
                }
            }
            *(short8*)&sAh[r][q * 8] = vh;
            *(short8*)&sAl[r][q * 8] = vl;
        }
        for (int g = tid; g < 512; g += 256) {
            const int r = g >> 2, q = g & 3;
            const int k = k0 + q * 8;
            short8 vh = (short8){0,0,0,0,0,0,0,0};
            short8 vl = (short8){0,0,0,0,0,0,0,0};
            const int n = n0 + r;
            if (n < N && k < K) {
                const float* src = W + (size_t)n * ldw + k;
                float va[8];
                #pragma unroll
                for (int j = 0; j < 8; ++j) va[j] = (k + j < K) ? src[j] : 0.f;
                #pragma unroll
                for (int j = 0; j < 8; ++j) {
                    const unsigned short hi = f2bf(va[j]);
                    ((short*)&vh)[j] = (short)hi;
                    ((short*)&vl)[j] = (short)f2bf(va[j] - bf2f(hi));
                }
            }
            *(short8*)&sWh[r][q * 8] = vh;
            *(short8*)&sWl[r][q * 8] = vl;
        }
        __syncthreads();

        short8 ah[4], al[4], bh[4], bl[4];
        #pragma unroll
        for (int mi = 0; mi < 4; ++mi) {
            ah[mi] = *(const short8*)&sAh[wm * 64 + mi * 16 + lrow][lkg * 8];
            al[mi] = *(const short8*)&sAl[wm * 64 + mi * 16 + lrow][lkg * 8];
        }
        #pragma unroll
        for (int ni = 0; ni < 4; ++ni) {
            bh[ni] = *(const short8*)&sWh[wn * 64 + ni * 16 + lrow][lkg * 8];
            bl[ni] = *(const short8*)&sWl[wn * 64 + ni * 16 + lrow][lkg * 8];
        }
        #pragma unroll
        for (int mi = 0; mi < 4; ++mi)
            #pragma unroll
            for (int ni = 0; ni < 4; ++ni) {
                acc[mi][ni] = __builtin_amdgcn_mfma_f32_16x16x32_bf16(ah[mi], bh[ni], acc[mi][ni], 0, 0, 0);
                acc[mi][ni] = __builtin_amdgcn_mfma_f32_16x16x32_bf16(ah[mi], bl[ni], acc[mi][ni], 0, 0, 0);
                acc[mi][ni] = __builtin_amdgcn_mfma_f32_16x16x32_bf16(al[mi], bh[ni], acc[mi][ni], 0, 0, 0);
            }
        __syncthreads();
    }

    #pragma unroll
    for (int mi = 0; mi < 4; ++mi) {
        const int mbase = m0 + wm * 64 + mi * 16 + lkg * 4;
        #pragma unroll
        for (int ni = 0; ni < 4; ++ni) {
            const int n = n0 + wn * 64 + ni * 16 + lrow;
            if (n >= N) continue;
            const float bb = bias ? bias[n] : 0.f;
            #pragma unroll
            for (int r = 0; r < 4; ++r) {
                const int m = mbase + r;
                if (m >= M) continue;
                C[(size_t)m * ldc + n] = acc[mi][ni][r] + bb;
            }
        }
    }
}

// ---------------------------------------------------------------------------
// Fused per-b attention front-end: att_h (LDS) -> e (LDS) -> softmax -> w_buf.
// 64 blocks x 512 threads. alpha_b omitted (softmax-invariant).
// ---------------------------------------------------------------------------
__global__ __launch_bounds__(512)
void fused_att_kernel(const float* __restrict__ h_in,
                      const float* __restrict__ h2att_w,
                      const float* __restrict__ h2att_b,
                      const unsigned short* __restrict__ p_att_bf,
                      const float* __restrict__ alpha_w,
                      float* __restrict__ w_buf)
{
    const int b = blockIdx.x;
    const int tid = threadIdx.x;
    const int wave = tid >> 6, lane = tid & 63;
    __shared__ float hs[1024];
    __shared__ float ahT[8][64];
    __shared__ float awT[8][64];
    __shared__ float esm[196];
    __shared__ float red2[2];

    if (tid < 256) ((float4*)hs)[tid] = ((const float4*)(h_in + b * kR))[tid];
    awT[tid & 7][tid >> 3] = alpha_w[tid];
    __syncthreads();

    // att_h: wave handles 64 j's, lanes split the 1024-dot (coalesced)
    for (int jj = 0; jj < 64; ++jj) {
        const int j = wave * 64 + jj;
        const float4* wr = (const float4*)(h2att_w + (size_t)j * kR);
        float a = 0.f;
        #pragma unroll
        for (int it = 0; it < 4; ++it) {
            const float4 wv = wr[it * 64 + lane];
            const float4 hv = ((const float4*)hs)[it * 64 + lane];
            a += wv.x * hv.x + wv.y * hv.y + wv.z * hv.z + wv.w * hv.w;
        }
        #pragma unroll
        for (int off = 32; off; off >>= 1) a += __shfl_xor(a, off, 64);
        if (lane == 0) ahT[j & 7][j >> 3] = a + h2att_b[j];
    }
    __syncthreads();

    // e: wave handles l = wave, wave+8, ...  (h = lane*8 + j)
    for (int l = wave; l < kL; l += 8) {
        const short8 pv = *(const short8*)(p_att_bf + ((size_t)b * kL + l) * kH + lane * 8);
        float a = 0.f;
        #pragma unroll
        for (int j = 0; j < 8; ++j)
            a += fast_tanh(bf2f(((const unsigned short*)&pv)[j]) + ahT[j][lane]) * awT[j][lane];
        #pragma unroll
        for (int off = 32; off; off >>= 1) a += __shfl_xor(a, off, 64);
        if (lane == 0) esm[l] = a;
    }
    __syncthreads();

    if (wave == 0) {
        float m = -1e30f;
        for (int l = lane; l < kL; l += 64) m = fmaxf(m, esm[l]);
        #pragma unroll
        for (int off = 32; off; off >>= 1) m = fmaxf(m, __shfl_xor(m, off, 64));
        float s = 0.f;
        for (int l = lane; l < kL; l += 64) s += __expf(esm[l] - m);
        #pragma unroll
        for (int off = 32; off; off >>= 1) s += __shfl_xor(s, off, 64);
        if (lane == 0) { red2[0] = m; red2[1] = 1.f / s; }
    }
    __syncthreads();
    if (tid < kL) w_buf[b * kL + tid] = __expf(esm[tid] - red2[0]) * red2[1];
}

// ---------------------------------------------------------------------------
// Attention readout partials: part[lg][b][f] = sum_{l in lg} w[l]*af[b,l,f]
// grid (4, 64); contiguous bf16x8 loads.
// ---------------------------------------------------------------------------
__global__ __launch_bounds__(256)
void att_res_part_kernel(const float* __restrict__ w_buf,
                         const unsigned short* __restrict__ af_bf,
                         float* __restrict__ part)
{
    const int lg = blockIdx.x, b = blockIdx.y;
    const int tid = threadIdx.x;
    __shared__ float wsm[kL];
    if (tid < kL) wsm[tid] = w_buf[b * kL + tid];
    __syncthreads();
    float acc[8] = {0.f,0.f,0.f,0.f,0.f,0.f,0.f,0.f};
    const unsigned short* base = af_bf + ((size_t)b * kL + lg * 49) * kF + tid * 8;
    #pragma unroll 2
    for (int li = 0; li < 49; ++li) {
        const short8 v = *(const short8*)(base + (size_t)li * kF);
        const float wl = wsm[lg * 49 + li];
        #pragma unroll
        for (int j = 0; j < 8; ++j) acc[j] += wl * bf2f(((const unsigned short*)&v)[j]);
    }
    float* po = part + ((size_t)(lg * 64 + b)) * kF + tid * 8;
    *(float4*)po       = make_float4(acc[0], acc[1], acc[2], acc[3]);
    *(float4*)(po + 4) = make_float4(acc[4], acc[5], acc[6], acc[7]);
}

// ---------------------------------------------------------------------------
// Fused LSTM step (h2h + a2c(4-partial sum) + i2h_pre + gates).
// 512 blocks; block owns r-columns {2blk, 2blk+1} for all 64 b.
// Writes h_out fp32 and h_all hi/lo bf16 (for logits GEMM).
// ---------------------------------------------------------------------------
__global__ __launch_bounds__(256)
void lstm_fused_kernel(const float* __restrict__ h_in,
                       const float* __restrict__ part,
                       const float* __restrict__ i2h_pre,
                       const float* __restrict__ h2h_w,
                       const float* __restrict__ h2h_b,
                       const float* __restrict__ a2c_w,
                       const float* __restrict__ a2c_b,
                       float* __restrict__ h_out,
                       float* __restrict__ cbuf,
                       unsigned short* __restrict__ h_all_hi,
                       unsigned short* __restrict__ h_all_lo,
                       int t)
{
    __shared__ float hs[64][68];
    __shared__ float ws[10][68];
    const int blk = blockIdx.x;
    const int tid = threadIdx.x;
    const int bq = tid >> 4, s = tid & 15;
    const int rc0 = blk * 2;
    const int kk = s * 4;
    float acc[4][10];
    #pragma unroll
    for (int i = 0; i < 4; ++i)
        #pragma unroll
        for (int rw = 0; rw < 10; ++rw) acc[i][rw] = 0.f;

    for (int k0 = 0; k0 < kR; k0 += 64) {
        for (int i = tid; i < 1024; i += 256) {
            const int bl = i >> 4, c4 = (i & 15) * 4;
            *(float4*)&hs[bl][c4] = *(const float4*)&h_in[bl * kR + k0 + c4];
        }
        for (int i = tid; i < 160; i += 256) {
            const int rw = i >> 4, c4 = (i & 15) * 4;
            *(float4*)&ws[rw][c4] =
                *(const float4*)&h2h_w[(size_t)((rw >> 1) * kR + rc0 + (rw & 1)) * kR + k0 + c4];
        }
        __syncthreads();
        float4 hv[4];
        #pragma unroll
        for (int i = 0; i < 4; ++i) hv[i] = *(const float4*)&hs[bq * 4 + i][kk];
        #pragma unroll
        for (int rw = 0; rw < 10; ++rw) {
            const float4 wv = *(const float4*)&ws[rw][kk];
            #pragma unroll
            for (int i = 0; i < 4; ++i)
                acc[i][rw] += hv[i].x * wv.x + hv[i].y * wv.y + hv[i].z * wv.z + hv[i].w * wv.w;
        }
        __syncthreads();
    }
    for (int k0 = 0; k0 < kF; k0 += 64) {
        for (int i = tid; i < 1024; i += 256) {
            const int bl = i >> 4, c4 = (i & 15) * 4;
            const float4 p0 = *(const float4*)&part[((size_t)(      bl)) * kF + k0 + c4];
            const float4 p1 = *(const float4*)&part[((size_t)( 64 + bl)) * kF + k0 + c4];
            const float4 p2 = *(const float4*)&part[((size_t)(128 + bl)) * kF + k0 + c4];
            const float4 p3 = *(const float4*)&part[((size_t)(192 + bl)) * kF + k0 + c4];
            float4 sv;
            sv.x = p0.x + p1.x + p2.x + p3.x;
            sv.y = p0.y + p1.y + p2.y + p3.y;
            sv.z = p0.z + p1.z + p2.z + p3.z;
            sv.w = p0.w + p1.w + p2.w + p3.w;
            *(float4*)&hs[bl][c4] = sv;
        }
        for (int i = tid; i < 64; i += 256) {
            const int rw = i >> 4, c4 = (i & 15) * 4;
            *(float4*)&ws[rw][c4] =
                *(const float4*)&a2c_w[(size_t)((rw >> 1) * kR + rc0 + (rw & 1)) * kF + k0 + c4];
        }
        __syncthreads();
        float4 av[4];
        #pragma unroll
        for (int i = 0; i < 4; ++i) av[i] = *(const float4*)&hs[bq * 4 + i][kk];
        #pragma unroll
        for (int rw = 0; rw < 4; ++rw) {
            const float4 wv = *(const float4*)&ws[rw][kk];
            #pragma unroll
            for (int i = 0; i < 4; ++i)
                acc[i][6 + rw] += av[i].x * wv.x + av[i].y * wv.y + av[i].z * wv.z + av[i].w * wv.w;
        }
        __syncthreads();
    }
    #pragma unroll
    for (int i = 0; i < 4; ++i)
        #pragma unroll
        for (int rw = 0; rw < 10; ++rw) {
            float v = acc[i][rw];
            v += __shfl_xor(v, 1, 64); v += __shfl_xor(v, 2, 64);
            v += __shfl_xor(v, 4, 64); v += __shfl_xor(v, 8, 64);
            acc[i][rw] = v;
        }
    if (s == 0) {
        #pragma unroll
        for (int i = 0; i < 4; ++i) {
            const int b = bq * 4 + i;
            const float* ib = i2h_pre + (size_t)(b * kT + t) * (5 * kR);
            #pragma unroll
            for (int rr = 0; rr < 2; ++rr) {
                const int r = rc0 + rr;
                const float S0 = acc[i][0 + rr] + ib[r]          + h2h_b[r];
                const float S1 = acc[i][2 + rr] + ib[kR + r]     + h2h_b[kR + r];
                const float S2 = acc[i][4 + rr] + ib[2 * kR + r] + h2h_b[2 * kR + r];
                const float S3 = acc[i][6 + rr] + ib[3 * kR + r] + h2h_b[3 * kR + r] + a2c_b[r];
                const float S4 = acc[i][8 + rr] + ib[4 * kR + r] + h2h_b[4 * kR + r] + a2c_b[kR + r];
                const float ing = fast_sig(S0);
                const float fg  = fast_sig(S1);
                const float og  = fast_sig(S2);
                const float gg  = fmaxf(S3, S4);
                const float nc  = fg * cbuf[b * kR + r] + ing * gg;
                const float nh  = og * fast_tanh(nc);
                cbuf[b * kR + r] = nc;
                h_out[b * kR + r] = nh;
                const size_t hidx = (size_t)(b * kT + t) * kR + r;
                const unsigned short hi = f2bf(nh);
                h_all_hi[hidx] = hi;
                h_all_lo[hidx] = f2bf(nh - bf2f(hi));
            }
        }
    }
}

// ---------------------------------------------------------------------------
// in-place log_softmax over V; one block per row (grid = kB*kT)
// ---------------------------------------------------------------------------
__global__ __launch_bounds__(256)
void log_softmax_kernel(float* __restrict__ out)
{
    __shared__ float red[256];
    const int tid = threadIdx.x;
    float* row = out + (size_t)blockIdx.x * kV;

    float mx = -1e30f;
    for (int v = tid; v < kV; v += 256) mx = fmaxf(mx, row[v]);
    red[tid] = mx; __syncthreads();
    for (int s = 128; s > 0; s >>= 1) {
        if (tid < s) red[tid] = fmaxf(red[tid], red[tid + s]);
        __syncthreads();
    }
    mx = red[0];
    __syncthreads();

    float sum = 0.f;
    for (int v = tid; v < kV; v += 256) sum += __expf(row[v] - mx);
    red[tid] = sum; __syncthreads();
    for (int s = 128; s > 0; s >>= 1) {
        if (tid < s) red[tid] += red[tid + s];
        __syncthreads();
    }
    const float ls = mx + logf(red[0]);

    for (int v = tid; v < kV; v += 256) row[v] -= ls;
}

extern "C" void kernel_launch(void* const* d_in, const int* in_sizes, int n_in,
                              void* d_out, int out_size, void* d_ws, size_t ws_size,
                              hipStream_t stream)
{
    const int*   seq       = (const int*)  d_in[0];
    const float* att_feats = (const float*)d_in[1];
    const float* embed_w   = (const float*)d_in[2];
    const float* ctx2att_w = (const float*)d_in[3];
    const float* ctx2att_b = (const float*)d_in[4];
    const float* h2att_w   = (const float*)d_in[5];
    const float* h2att_b   = (const float*)d_in[6];
    const float* alpha_w   = (const float*)d_in[7];
    const float* i2h_w     = (const float*)d_in[9];
    const float* i2h_b     = (const float*)d_in[10];
    const float* h2h_w     = (const float*)d_in[11];
    const float* h2h_b     = (const float*)d_in[12];
    const float* a2c_w     = (const float*)d_in[13];
    const float* a2c_b     = (const float*)d_in[14];
    const float* logit_w   = (const float*)d_in[15];
    const float* logit_b   = (const float*)d_in[16];
    float* out = (float*)d_out;

    float* ws = (float*)d_ws;
    size_t off = 0;
    auto alloc = [&](size_t nf) { float* p = ws + off; off += (nf + 3) & ~(size_t)3; return p; };

    unsigned short* af_bf     = (unsigned short*)alloc((size_t)kB * kL * kF / 2);  // 51 MB
    unsigned short* p_att_bf  = (unsigned short*)alloc((size_t)kB * kL * kH / 2);  // 12.8 MB
    unsigned short* ctx_hi    = (unsigned short*)alloc((size_t)kH * kF / 2);
    unsigned short* ctx_lo    = (unsigned short*)alloc((size_t)kH * kF / 2);
    unsigned short* logit_hi  = (unsigned short*)alloc((size_t)kV * kR / 2);
    unsigned short* logit_lo  = (unsigned short*)alloc((size_t)kV * kR / 2);
    unsigned short* h_all_hi  = (unsigned short*)alloc((size_t)kB * kT * kR / 2);
    unsigned short* h_all_lo  = (unsigned short*)alloc((size_t)kB * kT * kR / 2);
    float* i2h_pre = alloc((size_t)kB * kT * 5 * kR);   // 26 MB
    float* w_buf   = alloc((size_t)kB * kL);
    float* part    = alloc((size_t)4 * kB * kF);        // 2 MB
    float* h0      = alloc((size_t)kB * kR);
    float* h1      = alloc((size_t)kB * kR);
    float* cbuf    = alloc((size_t)kB * kR);

    hipMemsetAsync(h0,   0, (size_t)kB * kR * sizeof(float), stream);
    hipMemsetAsync(cbuf, 0, (size_t)kB * kR * sizeof(float), stream);

    // one-time conversions
    conv_hi_kernel<<<2048, 256, 0, stream>>>(att_feats, af_bf, kB * kL * kF / 4);
    conv_pair_kernel<<<512, 256, 0, stream>>>(ctx2att_w, ctx_hi, ctx_lo, kH * kF / 4);
    conv_pair_kernel<<<2048, 256, 0, stream>>>(logit_w, logit_hi, logit_lo, kV * kR / 4);

    // p_att = att_feats(hi) @ ctx2att(hi/lo).T + b -> bf16   (12544 x 512, K=2048)
    gemm_bf_kernel<false, true><<<dim3(kH / 128, kB * kL / 128), 256, 0, stream>>>(
        af_bf, nullptr, kF, ctx_hi, ctx_lo, kF, ctx2att_b, p_att_bf, kH,
        kB * kL, kH, kF);

    // i2h_pre = embed[seq] @ i2h_w.T + b   (1280 x 5120, K=300)
    gemm_split_kernel<true><<<dim3(5 * kR / 128, kB * kT / 128), 256, 0, stream>>>(
        embed_w, kE, i2h_w, kE, i2h_b, i2h_pre, 5 * kR, kB * kT, 5 * kR, kE, seq);

    // 20-step recurrence: 3 launches per step
    float* hin = h0;
    float* hout = h1;
    for (int t = 0; t < kT; ++t) {
        fused_att_kernel<<<dim3(kB), 512, 0, stream>>>(
            hin, h2att_w, h2att_b, p_att_bf, alpha_w, w_buf);
        att_res_part_kernel<<<dim3(4, kB), 256, 0, stream>>>(w_buf, af_bf, part);
        lstm_fused_kernel<<<dim3(512), 256, 0, stream>>>(
            hin, part, i2h_pre, h2h_w, h2h_b, a2c_w, a2c_b,
            hout, cbuf, h_all_hi, h_all_lo, t);
        float* tmp = hin; hin = hout; hout = tmp;
    }

    // logits = h_all(hi/lo) @ logit(hi/lo).T + b -> out fp32  (1280 x 12001, K=1024)
    gemm_bf_kernel<true, false><<<dim3((kV + 127) / 128, kB * kT / 128), 256, 0, stream>>>(
        h_all_hi, h_all_lo, kR, logit_hi, logit_lo, kR, logit_b, out, kV,
        kB * kT, kV, kR);

    log_softmax_kernel<<<dim3(kB * kT), 256, 0, stream>>>(out);
}

// Round 9
// 3550.231 us; speedup vs baseline: 3.2529x; 1.2941x over previous
//
#include <hip/hip_runtime.h>
#include <math.h>

namespace {
constexpr int kV = 12001;
constexpr int kE = 300;
constexpr int kR = 1024;
constexpr int kH = 512;
constexpr int kF = 2048;
constexpr int kB = 64;
constexpr int kT = 20;
constexpr int kL = 196;
}

typedef __attribute__((ext_vector_type(8))) short short8;
typedef __attribute__((ext_vector_type(4))) float f32x4;

__device__ __forceinline__ unsigned short f2bf(float f) {
    unsigned u = __builtin_bit_cast(unsigned, f);
    u = (u + 0x7fffu + ((u >> 16) & 1u)) >> 16;
    return (unsigned short)u;
}
__device__ __forceinline__ float bf2f(unsigned short h) {
    unsigned u = ((unsigned)h) << 16;
    return __builtin_bit_cast(float, u);
}
__device__ __forceinline__ float fast_tanh(float x) {
    x = fminf(15.f, fmaxf(-15.f, x));
    const float e = __expf(2.f * x);
    return (e - 1.f) / (e + 1.f);
}
__device__ __forceinline__ float fast_sig(float x) {
    return 1.f / (1.f + __expf(-x));
}

// ---------------------------------------------------------------------------
// fp32 -> bf16-hi conversion (n4 = count/4)
// ---------------------------------------------------------------------------
__global__ __launch_bounds__(256)
void conv_hi_kernel(const float* __restrict__ in, unsigned short* __restrict__ out, int n4)
{
    for (int i = blockIdx.x * 256 + threadIdx.x; i < n4; i += gridDim.x * 256) {
        const float4 v = ((const float4*)in)[i];
        ushort4 o;
        o.x = f2bf(v.x); o.y = f2bf(v.y); o.z = f2bf(v.z); o.w = f2bf(v.w);
        ((ushort4*)out)[i] = o;
    }
}

// fp32 -> (hi, lo) bf16 pair
__global__ __launch_bounds__(256)
void conv_pair_kernel(const float* __restrict__ in,
                      unsigned short* __restrict__ hi_out,
                      unsigned short* __restrict__ lo_out, int n4)
{
    for (int i = blockIdx.x * 256 + threadIdx.x; i < n4; i += gridDim.x * 256) {
        const float4 v = ((const float4*)in)[i];
        ushort4 h, l;
        h.x = f2bf(v.x); l.x = f2bf(v.x - bf2f(h.x));
        h.y = f2bf(v.y); l.y = f2bf(v.y - bf2f(h.y));
        h.z = f2bf(v.z); l.z = f2bf(v.z - bf2f(h.z));
        h.w = f2bf(v.w); l.w = f2bf(v.w - bf2f(h.w));
        ((ushort4*)hi_out)[i] = h;
        ((ushort4*)lo_out)[i] = l;
    }
}

// ---------------------------------------------------------------------------
// bf16-staged MFMA GEMM. products: Ah*Wh + Ah*Wl (+ Al*Wh if A_PAIR).
// ---------------------------------------------------------------------------
template<bool A_PAIR, bool OUT_BF16>
__global__ __launch_bounds__(256)
void gemm_bf_kernel(const unsigned short* __restrict__ Ah,
                    const unsigned short* __restrict__ Al, int lda,
                    const unsigned short* __restrict__ Wh,
                    const unsigned short* __restrict__ Wl, int ldw,
                    const float* __restrict__ bias,
                    void* __restrict__ Cp, int ldc,
                    int M, int N, int K)
{
    __shared__ unsigned short sAh[128][40];
    __shared__ unsigned short sAl[A_PAIR ? 128 : 1][40];
    __shared__ unsigned short sWh[128][40];
    __shared__ unsigned short sWl[128][40];
    const int tid = threadIdx.x;
    const int m0 = blockIdx.y * 128;
    const int n0 = blockIdx.x * 128;
    const int wave = tid >> 6, lane = tid & 63;
    const int wm = wave >> 1, wn = wave & 1;
    const int lrow = lane & 15, lkg = lane >> 4;

    f32x4 acc[4][4];
    #pragma unroll
    for (int mi = 0; mi < 4; ++mi)
        #pragma unroll
        for (int ni = 0; ni < 4; ++ni)
            acc[mi][ni] = (f32x4){0.f, 0.f, 0.f, 0.f};

    for (int k0 = 0; k0 < K; k0 += 32) {
        for (int g = tid; g < 512; g += 256) {
            const int r = g >> 2, q = g & 3;
            const int k = k0 + q * 8;
            const size_t off = (size_t)(m0 + r) * lda + k;
            *(short8*)&sAh[r][q * 8] = *(const short8*)(Ah + off);
            if (A_PAIR) *(short8*)&sAl[r][q * 8] = *(const short8*)(Al + off);
        }
        for (int g = tid; g < 512; g += 256) {
            const int r = g >> 2, q = g & 3;
            const int k = k0 + q * 8;
            const int n = n0 + r;
            short8 vh = (short8){0,0,0,0,0,0,0,0};
            short8 vl = (short8){0,0,0,0,0,0,0,0};
            if (n < N) {
                const size_t off = (size_t)n * ldw + k;
                vh = *(const short8*)(Wh + off);
                vl = *(const short8*)(Wl + off);
            }
            *(short8*)&sWh[r][q * 8] = vh;
            *(short8*)&sWl[r][q * 8] = vl;
        }
        __syncthreads();

        short8 ah[4], al[4], wh[4], wl[4];
        #pragma unroll
        for (int mi = 0; mi < 4; ++mi) {
            ah[mi] = *(const short8*)&sAh[wm * 64 + mi * 16 + lrow][lkg * 8];
            if (A_PAIR) al[mi] = *(const short8*)&sAl[wm * 64 + mi * 16 + lrow][lkg * 8];
        }
        #pragma unroll
        for (int ni = 0; ni < 4; ++ni) {
            wh[ni] = *(const short8*)&sWh[wn * 64 + ni * 16 + lrow][lkg * 8];
            wl[ni] = *(const short8*)&sWl[wn * 64 + ni * 16 + lrow][lkg * 8];
        }
        #pragma unroll
        for (int mi = 0; mi < 4; ++mi)
            #pragma unroll
            for (int ni = 0; ni < 4; ++ni) {
                acc[mi][ni] = __builtin_amdgcn_mfma_f32_16x16x32_bf16(ah[mi], wh[ni], acc[mi][ni], 0, 0, 0);
                acc[mi][ni] = __builtin_amdgcn_mfma_f32_16x16x32_bf16(ah[mi], wl[ni], acc[mi][ni], 0, 0, 0);
                if (A_PAIR)
                    acc[mi][ni] = __builtin_amdgcn_mfma_f32_16x16x32_bf16(al[mi], wh[ni], acc[mi][ni], 0, 0, 0);
            }
        __syncthreads();
    }

    #pragma unroll
    for (int mi = 0; mi < 4; ++mi) {
        const int mbase = m0 + wm * 64 + mi * 16 + lkg * 4;
        #pragma unroll
        for (int ni = 0; ni < 4; ++ni) {
            const int n = n0 + wn * 64 + ni * 16 + lrow;
            if (n >= N) continue;
            const float bb = bias ? bias[n] : 0.f;
            #pragma unroll
            for (int r = 0; r < 4; ++r) {
                const int m = mbase + r;
                const float v = acc[mi][ni][r] + bb;
                if (OUT_BF16) ((unsigned short*)Cp)[(size_t)m * ldc + n] = f2bf(v);
                else          ((float*)Cp)[(size_t)m * ldc + n] = v;
            }
        }
    }
}

// ---------------------------------------------------------------------------
// Split-fp32 GEMM (for i2h: gathered fp32 A, K=300)
// ---------------------------------------------------------------------------
template<bool GATHER>
__global__ __launch_bounds__(256)
void gemm_split_kernel(const float* __restrict__ A, int lda,
                       const float* __restrict__ W, int ldw,
                       const float* __restrict__ bias,
                       float* __restrict__ C, int ldc,
                       int M, int N, int K,
                       const int* __restrict__ ridx)
{
    __shared__ unsigned short sAh[128][40];
    __shared__ unsigned short sAl[128][40];
    __shared__ unsigned short sWh[128][40];
    __shared__ unsigned short sWl[128][40];
    const int tid = threadIdx.x;
    const int m0 = blockIdx.y * 128;
    const int n0 = blockIdx.x * 128;
    const int wave = tid >> 6, lane = tid & 63;
    const int wm = wave >> 1, wn = wave & 1;
    const int lrow = lane & 15, lkg = lane >> 4;

    f32x4 acc[4][4];
    #pragma unroll
    for (int mi = 0; mi < 4; ++mi)
        #pragma unroll
        for (int ni = 0; ni < 4; ++ni)
            acc[mi][ni] = (f32x4){0.f, 0.f, 0.f, 0.f};

    for (int k0 = 0; k0 < K; k0 += 32) {
        for (int g = tid; g < 512; g += 256) {
            const int r = g >> 2, q = g & 3;
            const int k = k0 + q * 8;
            short8 vh = (short8){0,0,0,0,0,0,0,0};
            short8 vl = (short8){0,0,0,0,0,0,0,0};
            const int m = m0 + r;
            if (m < M && k < K) {
                const int row = GATHER ? ridx[m] : m;
                const float* src = A + (size_t)row * lda + k;
                float va[8];
                #pragma unroll
                for (int j = 0; j < 8; ++j) va[j] = (k + j < K) ? src[j] : 0.f;
                #pragma unroll
                for (int j = 0; j < 8; ++j) {
                    const unsigned short hi = f2bf(va[j]);
                    ((short*)&vh)[j] = (short)hi;
                    ((short*)&vl)[j] = (short)f2bf(va[j] - bf2f(hi));
                }
            }
            *(short8*)&sAh[r][q * 8] = vh;
            *(short8*)&sAl[r][q * 8] = vl;
        }
        for (int g = tid; g < 512; g += 256) {
            const int r = g >> 2, q = g & 3;
            const int k = k0 + q * 8;
            short8 vh = (short8){0,0,0,0,0,0,0,0};
            short8 vl = (short8){0,0,0,0,0,0,0,0};
            const int n = n0 + r;
            if (n < N && k < K) {
                const float* src = W + (size_t)n * ldw + k;
                float va[8];
                #pragma unroll
                for (int j = 0; j < 8; ++j) va[j] = (k + j < K) ? src[j] : 0.f;
                #pragma unroll
                for (int j = 0; j < 8; ++j) {
                    const unsigned short hi = f2bf(va[j]);
                    ((short*)&vh)[j] = (short)hi;
                    ((short*)&vl)[j] = (short)f2bf(va[j] - bf2f(hi));
                }
            }
            *(short8*)&sWh[r][q * 8] = vh;
            *(short8*)&sWl[r][q * 8] = vl;
        }
        __syncthreads();

        short8 ah[4], al[4], bh[4], bl[4];
        #pragma unroll
        for (int mi = 0; mi < 4; ++mi) {
            ah[mi] = *(const short8*)&sAh[wm * 64 + mi * 16 + lrow][lkg * 8];
            al[mi] = *(const short8*)&sAl[wm * 64 + mi * 16 + lrow][lkg * 8];
        }
        #pragma unroll
        for (int ni = 0; ni < 4; ++ni) {
            bh[ni] = *(const short8*)&sWh[wn * 64 + ni * 16 + lrow][lkg * 8];
            bl[ni] = *(const short8*)&sWl[wn * 64 + ni * 16 + lrow][lkg * 8];
        }
        #pragma unroll
        for (int mi = 0; mi < 4; ++mi)
            #pragma unroll
            for (int ni = 0; ni < 4; ++ni) {
                acc[mi][ni] = __builtin_amdgcn_mfma_f32_16x16x32_bf16(ah[mi], bh[ni], acc[mi][ni], 0, 0, 0);
                acc[mi][ni] = __builtin_amdgcn_mfma_f32_16x16x32_bf16(ah[mi], bl[ni], acc[mi][ni], 0, 0, 0);
                acc[mi][ni] = __builtin_amdgcn_mfma_f32_16x16x32_bf16(al[mi], bh[ni], acc[mi][ni], 0, 0, 0);
            }
        __syncthreads();
    }

    #pragma unroll
    for (int mi = 0; mi < 4; ++mi) {
        const int mbase = m0 + wm * 64 + mi * 16 + lkg * 4;
        #pragma unroll
        for (int ni = 0; ni < 4; ++ni) {
            const int n = n0 + wn * 64 + ni * 16 + lrow;
            if (n >= N) continue;
            const float bb = bias ? bias[n] : 0.f;
            #pragma unroll
            for (int r = 0; r < 4; ++r) {
                const int m = mbase + r;
                if (m >= M) continue;
                C[(size_t)m * ldc + n] = acc[mi][ni][r] + bb;
            }
        }
    }
}

// ---------------------------------------------------------------------------
// att_h v3: grid (64 jg, 8 bg). Block stages 8 w-rows + 8 h-rows in LDS,
// computes the 8x8 (j,b) dot tile. Weight traffic 16 MB/step.
// ---------------------------------------------------------------------------
__global__ __launch_bounds__(256)
void att_h_kernel(const float* __restrict__ h_in,
                  const float* __restrict__ w,
                  const float* __restrict__ bias,
                  float* __restrict__ att_h)
{
    __shared__ float wl[8][1024];
    __shared__ float hl[8][1024];
    const int jg = blockIdx.x, bg = blockIdx.y;
    const int tid = threadIdx.x;
    for (int i = tid; i < 2048; i += 256) {
        const int r = i >> 8, c4 = i & 255;
        ((float4*)&wl[r][0])[c4] = ((const float4*)(w    + (size_t)(jg * 8 + r) * kR))[c4];
        ((float4*)&hl[r][0])[c4] = ((const float4*)(h_in + (size_t)(bg * 8 + r) * kR))[c4];
    }
    __syncthreads();
    const int wave = tid >> 6, lane = tid & 63;
    #pragma unroll
    for (int i = 0; i < 16; ++i) {
        const int p = wave * 16 + i;
        const int j = p >> 3, b = p & 7;
        float a = 0.f;
        #pragma unroll
        for (int it = 0; it < 4; ++it) {
            const float4 wv = ((const float4*)&wl[j][0])[it * 64 + lane];
            const float4 hv = ((const float4*)&hl[b][0])[it * 64 + lane];
            a += wv.x * hv.x + wv.y * hv.y + wv.z * hv.z + wv.w * hv.w;
        }
        #pragma unroll
        for (int off = 32; off; off >>= 1) a += __shfl_xor(a, off, 64);
        if (lane == 0) att_h[(bg * 8 + b) * kH + jg * 8 + j] = a + bias[jg * 8 + j];
    }
}

// ---------------------------------------------------------------------------
// K2: fused e + softmax + readout. One block per b, 512 threads.
// e[l] = sum_h tanh(p_att+att_h)*alpha; softmax over l; att_res_bf[b,f].
// ---------------------------------------------------------------------------
__global__ __launch_bounds__(512)
void att_fused2_kernel(const float* __restrict__ att_h,
                       const unsigned short* __restrict__ p_att_bf,
                       const float* __restrict__ alpha_w,
                       const unsigned short* __restrict__ af_bf,
                       unsigned short* __restrict__ att_res_bf)
{
    const int b = blockIdx.x;
    const int tid = threadIdx.x;
    const int wave = tid >> 6, lane = tid & 63;
    __shared__ float ahT[8][64];
    __shared__ float awT[8][64];
    __shared__ float esm[kL];
    __shared__ float wsm[kL];
    __shared__ float red2[2];

    ahT[tid & 7][tid >> 3] = att_h[b * kH + tid];
    awT[tid & 7][tid >> 3] = alpha_w[tid];
    __syncthreads();

    // e: wave handles l = wave, wave+8, ...
    for (int l = wave; l < kL; l += 8) {
        const short8 pv = *(const short8*)(p_att_bf + ((size_t)b * kL + l) * kH + lane * 8);
        float a = 0.f;
        #pragma unroll
        for (int j = 0; j < 8; ++j)
            a += fast_tanh(bf2f(((const unsigned short*)&pv)[j]) + ahT[j][lane]) * awT[j][lane];
        #pragma unroll
        for (int off = 32; off; off >>= 1) a += __shfl_xor(a, off, 64);
        if (lane == 0) esm[l] = a;
    }
    __syncthreads();

    if (wave == 0) {
        float m = -1e30f;
        for (int l = lane; l < kL; l += 64) m = fmaxf(m, esm[l]);
        #pragma unroll
        for (int off = 32; off; off >>= 1) m = fmaxf(m, __shfl_xor(m, off, 64));
        float s = 0.f;
        for (int l = lane; l < kL; l += 64) s += __expf(esm[l] - m);
        #pragma unroll
        for (int off = 32; off; off >>= 1) s += __shfl_xor(s, off, 64);
        if (lane == 0) { red2[0] = m; red2[1] = 1.f / s; }
    }
    __syncthreads();
    if (tid < kL) wsm[tid] = __expf(esm[tid] - red2[0]) * red2[1];
    __syncthreads();

    // readout: thread owns 4 f-cols; stream af_bf rows (coalesced 4KB/row)
    float a0 = 0.f, a1 = 0.f, a2 = 0.f, a3 = 0.f;
    const unsigned short* base = af_bf + (size_t)b * kL * kF + tid * 4;
    #pragma unroll 4
    for (int l = 0; l < kL; ++l) {
        const ushort4 v = *(const ushort4*)(base + (size_t)l * kF);
        const float wl = wsm[l];
        a0 += wl * bf2f(v.x); a1 += wl * bf2f(v.y);
        a2 += wl * bf2f(v.z); a3 += wl * bf2f(v.w);
    }
    ushort4 o;
    o.x = f2bf(a0); o.y = f2bf(a1); o.z = f2bf(a2); o.w = f2bf(a3);
    *(ushort4*)(att_res_bf + (size_t)b * kF + tid * 4) = o;
}

// ---------------------------------------------------------------------------
// Fused LSTM step (h2h + a2c(bf16 att_res) + i2h_pre + gates).
// 512 blocks x 2 r-cols. Writes h_out fp32 and h_all hi/lo bf16.
// ---------------------------------------------------------------------------
__global__ __launch_bounds__(256)
void lstm_fused_kernel(const float* __restrict__ h_in,
                       const unsigned short* __restrict__ ares_bf,
                       const float* __restrict__ i2h_pre,
                       const float* __restrict__ h2h_w,
                       const float* __restrict__ h2h_b,
                       const float* __restrict__ a2c_w,
                       const float* __restrict__ a2c_b,
                       float* __restrict__ h_out,
                       float* __restrict__ cbuf,
                       unsigned short* __restrict__ h_all_hi,
                       unsigned short* __restrict__ h_all_lo,
                       int t)
{
    __shared__ float hs[64][68];
    __shared__ float ws[10][68];
    const int blk = blockIdx.x;
    const int tid = threadIdx.x;
    const int bq = tid >> 4, s = tid & 15;
    const int rc0 = blk * 2;
    const int kk = s * 4;
    float acc[4][10];
    #pragma unroll
    for (int i = 0; i < 4; ++i)
        #pragma unroll
        for (int rw = 0; rw < 10; ++rw) acc[i][rw] = 0.f;

    for (int k0 = 0; k0 < kR; k0 += 64) {
        for (int i = tid; i < 1024; i += 256) {
            const int bl = i >> 4, c4 = (i & 15) * 4;
            *(float4*)&hs[bl][c4] = *(const float4*)&h_in[bl * kR + k0 + c4];
        }
        for (int i = tid; i < 160; i += 256) {
            const int rw = i >> 4, c4 = (i & 15) * 4;
            *(float4*)&ws[rw][c4] =
                *(const float4*)&h2h_w[(size_t)((rw >> 1) * kR + rc0 + (rw & 1)) * kR + k0 + c4];
        }
        __syncthreads();
        float4 hv[4];
        #pragma unroll
        for (int i = 0; i < 4; ++i) hv[i] = *(const float4*)&hs[bq * 4 + i][kk];
        #pragma unroll
        for (int rw = 0; rw < 10; ++rw) {
            const float4 wv = *(const float4*)&ws[rw][kk];
            #pragma unroll
            for (int i = 0; i < 4; ++i)
                acc[i][rw] += hv[i].x * wv.x + hv[i].y * wv.y + hv[i].z * wv.z + hv[i].w * wv.w;
        }
        __syncthreads();
    }
    for (int k0 = 0; k0 < kF; k0 += 64) {
        for (int i = tid; i < 1024; i += 256) {
            const int bl = i >> 4, c4 = (i & 15) * 4;
            const ushort4 v = *(const ushort4*)&ares_bf[(size_t)bl * kF + k0 + c4];
            *(float4*)&hs[bl][c4] = make_float4(bf2f(v.x), bf2f(v.y), bf2f(v.z), bf2f(v.w));
        }
        for (int i = tid; i < 64; i += 256) {
            const int rw = i >> 4, c4 = (i & 15) * 4;
            *(float4*)&ws[rw][c4] =
                *(const float4*)&a2c_w[(size_t)((rw >> 1) * kR + rc0 + (rw & 1)) * kF + k0 + c4];
        }
        __syncthreads();
        float4 av[4];
        #pragma unroll
        for (int i = 0; i < 4; ++i) av[i] = *(const float4*)&hs[bq * 4 + i][kk];
        #pragma unroll
        for (int rw = 0; rw < 4; ++rw) {
            const float4 wv = *(const float4*)&ws[rw][kk];
            #pragma unroll
            for (int i = 0; i < 4; ++i)
                acc[i][6 + rw] += av[i].x * wv.x + av[i].y * wv.y + av[i].z * wv.z + av[i].w * wv.w;
        }
        __syncthreads();
    }
    #pragma unroll
    for (int i = 0; i < 4; ++i)
        #pragma unroll
        for (int rw = 0; rw < 10; ++rw) {
            float v = acc[i][rw];
            v += __shfl_xor(v, 1, 64); v += __shfl_xor(v, 2, 64);
            v += __shfl_xor(v, 4, 64); v += __shfl_xor(v, 8, 64);
            acc[i][rw] = v;
        }
    if (s == 0) {
        #pragma unroll
        for (int i = 0; i < 4; ++i) {
            const int b = bq * 4 + i;
            const float* ib = i2h_pre + (size_t)(b * kT + t) * (5 * kR);
            #pragma unroll
            for (int rr = 0; rr < 2; ++rr) {
                const int r = rc0 + rr;
                const float S0 = acc[i][0 + rr] + ib[r]          + h2h_b[r];
                const float S1 = acc[i][2 + rr] + ib[kR + r]     + h2h_b[kR + r];
                const float S2 = acc[i][4 + rr] + ib[2 * kR + r] + h2h_b[2 * kR + r];
                const float S3 = acc[i][6 + rr] + ib[3 * kR + r] + h2h_b[3 * kR + r] + a2c_b[r];
                const float S4 = acc[i][8 + rr] + ib[4 * kR + r] + h2h_b[4 * kR + r] + a2c_b[kR + r];
                const float ing = fast_sig(S0);
                const float fg  = fast_sig(S1);
                const float og  = fast_sig(S2);
                const float gg  = fmaxf(S3, S4);
                const float nc  = fg * cbuf[b * kR + r] + ing * gg;
                const float nh  = og * fast_tanh(nc);
                cbuf[b * kR + r] = nc;
                h_out[b * kR + r] = nh;
                const size_t hidx = (size_t)(b * kT + t) * kR + r;
                const unsigned short hi = f2bf(nh);
                h_all_hi[hidx] = hi;
                h_all_lo[hidx] = f2bf(nh - bf2f(hi));
            }
        }
    }
}

// ---------------------------------------------------------------------------
// in-place log_softmax over V; one block per row (grid = kB*kT)
// ---------------------------------------------------------------------------
__global__ __launch_bounds__(256)
void log_softmax_kernel(float* __restrict__ out)
{
    __shared__ float red[256];
    const int tid = threadIdx.x;
    float* row = out + (size_t)blockIdx.x * kV;

    float mx = -1e30f;
    for (int v = tid; v < kV; v += 256) mx = fmaxf(mx, row[v]);
    red[tid] = mx; __syncthreads();
    for (int s = 128; s > 0; s >>= 1) {
        if (tid < s) red[tid] = fmaxf(red[tid], red[tid + s]);
        __syncthreads();
    }
    mx = red[0];
    __syncthreads();

    float sum = 0.f;
    for (int v = tid; v < kV; v += 256) sum += __expf(row[v] - mx);
    red[tid] = sum; __syncthreads();
    for (int s = 128; s > 0; s >>= 1) {
        if (tid < s) red[tid] += red[tid + s];
        __syncthreads();
    }
    const float ls = mx + logf(red[0]);

    for (int v = tid; v < kV; v += 256) row[v] -= ls;
}

extern "C" void kernel_launch(void* const* d_in, const int* in_sizes, int n_in,
                              void* d_out, int out_size, void* d_ws, size_t ws_size,
                              hipStream_t stream)
{
    const int*   seq       = (const int*)  d_in[0];
    const float* att_feats = (const float*)d_in[1];
    const float* embed_w   = (const float*)d_in[2];
    const float* ctx2att_w = (const float*)d_in[3];
    const float* ctx2att_b = (const float*)d_in[4];
    const float* h2att_w   = (const float*)d_in[5];
    const float* h2att_b   = (const float*)d_in[6];
    const float* alpha_w   = (const float*)d_in[7];
    const float* i2h_w     = (const float*)d_in[9];
    const float* i2h_b     = (const float*)d_in[10];
    const float* h2h_w     = (const float*)d_in[11];
    const float* h2h_b     = (const float*)d_in[12];
    const float* a2c_w     = (const float*)d_in[13];
    const float* a2c_b     = (const float*)d_in[14];
    const float* logit_w   = (const float*)d_in[15];
    const float* logit_b   = (const float*)d_in[16];
    float* out = (float*)d_out;

    float* ws = (float*)d_ws;
    size_t off = 0;
    auto alloc = [&](size_t nf) { float* p = ws + off; off += (nf + 3) & ~(size_t)3; return p; };

    unsigned short* af_bf      = (unsigned short*)alloc((size_t)kB * kL * kF / 2);  // 51 MB
    unsigned short* p_att_bf   = (unsigned short*)alloc((size_t)kB * kL * kH / 2);  // 12.8 MB
    unsigned short* ctx_hi     = (unsigned short*)alloc((size_t)kH * kF / 2);
    unsigned short* ctx_lo     = (unsigned short*)alloc((size_t)kH * kF / 2);
    unsigned short* logit_hi   = (unsigned short*)alloc((size_t)kV * kR / 2);
    unsigned short* logit_lo   = (unsigned short*)alloc((size_t)kV * kR / 2);
    unsigned short* h_all_hi   = (unsigned short*)alloc((size_t)kB * kT * kR / 2);
    unsigned short* h_all_lo   = (unsigned short*)alloc((size_t)kB * kT * kR / 2);
    unsigned short* att_res_bf = (unsigned short*)alloc((size_t)kB * kF / 2);
    float* i2h_pre = alloc((size_t)kB * kT * 5 * kR);   // 26 MB
    float* att_h   = alloc((size_t)kB * kH);
    float* h0      = alloc((size_t)kB * kR);
    float* h1      = alloc((size_t)kB * kR);
    float* cbuf    = alloc((size_t)kB * kR);

    hipMemsetAsync(h0,   0, (size_t)kB * kR * sizeof(float), stream);
    hipMemsetAsync(cbuf, 0, (size_t)kB * kR * sizeof(float), stream);

    // one-time conversions
    conv_hi_kernel<<<2048, 256, 0, stream>>>(att_feats, af_bf, kB * kL * kF / 4);
    conv_pair_kernel<<<512, 256, 0, stream>>>(ctx2att_w, ctx_hi, ctx_lo, kH * kF / 4);
    conv_pair_kernel<<<2048, 256, 0, stream>>>(logit_w, logit_hi, logit_lo, kV * kR / 4);

    // p_att = att_feats(hi) @ ctx2att(hi/lo).T + b -> bf16   (12544 x 512, K=2048)
    gemm_bf_kernel<false, true><<<dim3(kH / 128, kB * kL / 128), 256, 0, stream>>>(
        af_bf, nullptr, kF, ctx_hi, ctx_lo, kF, ctx2att_b, p_att_bf, kH,
        kB * kL, kH, kF);

    // i2h_pre = embed[seq] @ i2h_w.T + b   (1280 x 5120, K=300)
    gemm_split_kernel<true><<<dim3(5 * kR / 128, kB * kT / 128), 256, 0, stream>>>(
        embed_w, kE, i2h_w, kE, i2h_b, i2h_pre, 5 * kR, kB * kT, 5 * kR, kE, seq);

    // 20-step recurrence: 3 launches per step
    float* hin = h0;
    float* hout = h1;
    for (int t = 0; t < kT; ++t) {
        att_h_kernel<<<dim3(64, 8), 256, 0, stream>>>(hin, h2att_w, h2att_b, att_h);
        att_fused2_kernel<<<dim3(kB), 512, 0, stream>>>(
            att_h, p_att_bf, alpha_w, af_bf, att_res_bf);
        lstm_fused_kernel<<<dim3(512), 256, 0, stream>>>(
            hin, att_res_bf, i2h_pre, h2h_w, h2h_b, a2c_w, a2c_b,
            hout, cbuf, h_all_hi, h_all_lo, t);
        float* tmp = hin; hin = hout; hout = tmp;
    }

    // logits = h_all(hi/lo) @ logit(hi/lo).T + b -> out fp32  (1280 x 12001, K=1024)
    gemm_bf_kernel<true, false><<<dim3((kV + 127) / 128, kB * kT / 128), 256, 0, stream>>>(
        h_all_hi, h_all_lo, kR, logit_hi, logit_lo, kR, logit_b, out, kV,
        kB * kT, kV, kR);

    log_softmax_kernel<<<dim3(kB * kT), 256, 0, stream>>>(out);
}